// Round 7
// baseline (1262.546 us; speedup 1.0000x reference)
//
#include <hip/hip_runtime.h>
#include <hip/hip_bf16.h>
#include <math.h>

#define L_SEQ 6464
#define DM 64
#define DI 128
#define DS 16
#define CHUNK 64
#define NCH 101   // 6464 = 101 * 64; chunk starts are 16B-aligned
#define YSTR 68   // s_y stride: 17*16B aligned, 2-way bank alias only

// ---------------- prologue: concat + pos, then @W_fcc + b_fcc ----------------
__global__ void k_embed(const float* __restrict__ DNA, const float* __restrict__ CpG,
                        const float* __restrict__ cell, const float* __restrict__ pos,
                        const float* __restrict__ Wfcc, const float* __restrict__ bfcc,
                        float* __restrict__ x0) {
    int l = blockIdx.x;
    int j = threadIdx.x;  // 64
    __shared__ float in64[64];
    float v;
    if (j < 16)       v = CpG[l * 16 + j];
    else if (j < 32)  v = cell[l * 16 + (j - 16)];
    else              v = DNA[l * 32 + (j - 32)];
    v += pos[l * 64 + j];
    in64[j] = v;
    __syncthreads();
    float acc = bfcc[j];
    for (int i = 0; i < 64; i++) acc += in64[i] * Wfcc[i * 64 + j];
    x0[(size_t)l * 64 + j] = acc;
}

// ---------------- xz = x @ W_in : 8 rows/block, f4 LDS reads ----------------
__global__ void __launch_bounds__(256) k_gemm_in(const float* __restrict__ x,
                                                 const float* __restrict__ Win,
                                                 float* __restrict__ xz) {
    __shared__ __align__(16) float s_x[8][64];
    int t0 = blockIdx.x * 8;
    int tid = threadIdx.x;
    for (int i = tid; i < 8 * 64; i += 256) {
        int rr = i >> 6, c = i & 63;
        s_x[rr][c] = x[(size_t)(t0 + rr) * 64 + c];
    }
    __syncthreads();
    int j = tid;  // 256 cols
    float acc[8];
    #pragma unroll
    for (int r = 0; r < 8; r++) acc[r] = 0.f;
    for (int i = 0; i < 64; i += 4) {
        float w0 = Win[(i + 0) * 256 + j];
        float w1 = Win[(i + 1) * 256 + j];
        float w2 = Win[(i + 2) * 256 + j];
        float w3 = Win[(i + 3) * 256 + j];
        #pragma unroll
        for (int r = 0; r < 8; r++) {
            float4 xv = *(const float4*)&s_x[r][i];
            acc[r] = fmaf(xv.x, w0, fmaf(xv.y, w1, fmaf(xv.z, w2, fmaf(xv.w, w3, acc[r]))));
        }
    }
    #pragma unroll
    for (int r = 0; r < 8; r++) xz[(size_t)(t0 + r) * 256 + j] = acc[r];
}

// ------- fused conv(+silu) both dirs + xdbl + dt/B/C -> TRANSPOSED outputs -------
__global__ void __launch_bounds__(256) k_convdt(
        const float* __restrict__ xz, const float* __restrict__ convw,
        const float* __restrict__ convb, const float* __restrict__ Wxp,
        const float* __restrict__ Wdt, const float* __restrict__ bdt,
        float* __restrict__ dtT, float* __restrict__ xcT,
        float* __restrict__ BT, float* __restrict__ CT) {
    __shared__ __align__(16) float s_xi[22][128];    // xi rows t0-3 .. t0+18
    __shared__ __align__(16) float s_xc[16][128];
    __shared__ __align__(16) float s_dtl[16][128];
    __shared__ __align__(16) float s_xd[16][36];
    __shared__ __align__(16) float s_wxpT[36 * 132]; // wxpT[t][i], stride 132 (16B-aligned)
    int t0 = blockIdx.x * 16;
    int tid = threadIdx.x;
    for (int i = tid; i < 128 * 36; i += 256) {
        int ii = i / 36, t = i - ii * 36;
        s_wxpT[t * 132 + ii] = Wxp[i];
    }
    for (int i = tid; i < 22 * 32; i += 256) {
        int rr = i >> 5, q = i & 31;
        int r = t0 - 3 + rr;
        float4 v = make_float4(0.f, 0.f, 0.f, 0.f);
        if (r >= 0 && r < L_SEQ) v = *(const float4*)&xz[(size_t)r * 256 + 4 * q];
        s_xi[rr][4 * q + 0] = v.x;
        s_xi[rr][4 * q + 1] = v.y;
        s_xi[rr][4 * q + 2] = v.z;
        s_xi[rr][4 * q + 3] = v.w;
    }
    __syncthreads();
    for (int dir = 0; dir < 2; dir++) {
        // conv + silu
        for (int i = tid; i < 16 * 128; i += 256) {
            int rr = i >> 7, d = i & 127;
            int lr = rr + 3;
            float acc = convb[d];
            if (dir == 0) {
                #pragma unroll
                for (int k = 0; k < 4; k++) acc += convw[d * 4 + k] * s_xi[lr - 3 + k][d];
            } else {
                #pragma unroll
                for (int k = 0; k < 4; k++) acc += convw[d * 4 + k] * s_xi[lr + 3 - k][d];
            }
            s_xc[rr][d] = acc / (1.f + expf(-acc));
        }
        __syncthreads();
        // xdbl = xc @ W_xp (36 cols), b128 both operands
        for (int o = tid; o < 16 * 36; o += 256) {
            int rr = o / 36, t = o - rr * 36;
            float acc = 0.f;
            for (int i = 0; i < 128; i += 4) {
                float4 xv = *(const float4*)&s_xc[rr][i];
                float4 wv = *(const float4*)&s_wxpT[t * 132 + i];
                acc += xv.x * wv.x + xv.y * wv.y + xv.z * wv.z + xv.w * wv.w;
            }
            s_xd[rr][t] = acc;
        }
        __syncthreads();
        // dt = softplus(xdbl[:, :4] @ W_dt + b_dt)
        for (int o = tid; o < 16 * 128; o += 256) {
            int rr = o >> 7, d = o & 127;
            float pre = bdt[d];
            #pragma unroll
            for (int r = 0; r < 4; r++) pre += s_xd[rr][r] * Wdt[r * 128 + d];
            s_dtl[rr][d] = (pre > 20.f) ? pre : log1pf(expf(pre));
        }
        __syncthreads();
        // transposed stores: dtT/xcT [dir][d][L]
        for (int i = tid; i < 512; i += 256) {
            int q = i >> 7, d = i & 127;
            float4 a, b;
            a.x = s_dtl[4 * q + 0][d]; a.y = s_dtl[4 * q + 1][d];
            a.z = s_dtl[4 * q + 2][d]; a.w = s_dtl[4 * q + 3][d];
            b.x = s_xc[4 * q + 0][d];  b.y = s_xc[4 * q + 1][d];
            b.z = s_xc[4 * q + 2][d];  b.w = s_xc[4 * q + 3][d];
            size_t base = (size_t)(dir * 128 + d) * L_SEQ + t0 + 4 * q;
            *(float4*)&dtT[base] = a;
            *(float4*)&xcT[base] = b;
        }
        // BT/CT [dir][s][L]
        if (tid < 128) {
            int cc = tid >> 2, q = tid & 3;
            float4 v;
            v.x = s_xd[4 * q + 0][4 + cc]; v.y = s_xd[4 * q + 1][4 + cc];
            v.z = s_xd[4 * q + 2][4 + cc]; v.w = s_xd[4 * q + 3][4 + cc];
            float* dst = (cc < 16) ? BT : CT;
            *(float4*)&dst[(size_t)(dir * 16 + (cc & 15)) * L_SEQ + t0 + 4 * q] = v;
        }
        __syncthreads();
    }
}

// ---------------- DPP 16-lane row rotate ----------------
template<int CTRL>
__device__ __forceinline__ float ror16f(float v) {
    return __int_as_float(__builtin_amdgcn_update_dpp(0, __float_as_int(v), CTRL, 0xf, 0xf, true));
}

// ---------------- scan pass 1: register-batched per-chunk (a_prod, h_end) ----------------
__global__ void __launch_bounds__(256) k_scan1s(
        const float* __restrict__ dtT, const float* __restrict__ xcT,
        const float* __restrict__ BT, const float* __restrict__ Alog,
        float* __restrict__ cA, float* __restrict__ cB) {
    int bxd = blockIdx.x;   // d-group (8)
    int c   = blockIdx.y;   // chunk (101)
    int dir = blockIdx.z;   // 2
    int tid = threadIdx.x;
    int s = tid & 15, dl = tid >> 4;
    int d = bxd * 16 + dl;
    const float* dp = dtT + (size_t)(dir * 128 + d) * L_SEQ;
    const float* xp = xcT + (size_t)(dir * 128 + d) * L_SEQ;
    const float* bp = BT  + (size_t)(dir * 16 + s) * L_SEQ;
    float A = -expf(Alog[d * 16 + s]);
    float h = 0.f, ap = 1.f;
    if (dir == 0) {
        int base = c * 64;
        for (int b = 0; b < 4; b++) {
            float4 dv[4], xv[4], bv[4];
            #pragma unroll
            for (int j = 0; j < 4; j++) {
                int o = base + 16 * b + 4 * j;
                dv[j] = *(const float4*)&dp[o];
                xv[j] = *(const float4*)&xp[o];
                bv[j] = *(const float4*)&bp[o];
            }
            #pragma unroll
            for (int j = 0; j < 4; j++) {
                float a;
                a = __expf(dv[j].x * A); h = fmaf(a, h, dv[j].x * xv[j].x * bv[j].x); ap *= a;
                a = __expf(dv[j].y * A); h = fmaf(a, h, dv[j].y * xv[j].y * bv[j].y); ap *= a;
                a = __expf(dv[j].z * A); h = fmaf(a, h, dv[j].z * xv[j].z * bv[j].z); ap *= a;
                a = __expf(dv[j].w * A); h = fmaf(a, h, dv[j].w * xv[j].w * bv[j].w); ap *= a;
            }
        }
    } else {
        for (int b = 0; b < 4; b++) {
            float4 dv[4], xv[4], bv[4];
            #pragma unroll
            for (int j = 0; j < 4; j++) {
                int o = L_SEQ - 64 * c - 4 - 16 * b - 4 * j;
                dv[j] = *(const float4*)&dp[o];
                xv[j] = *(const float4*)&xp[o];
                bv[j] = *(const float4*)&bp[o];
            }
            #pragma unroll
            for (int j = 0; j < 4; j++) {
                float a;
                a = __expf(dv[j].w * A); h = fmaf(a, h, dv[j].w * xv[j].w * bv[j].w); ap *= a;
                a = __expf(dv[j].z * A); h = fmaf(a, h, dv[j].z * xv[j].z * bv[j].z); ap *= a;
                a = __expf(dv[j].y * A); h = fmaf(a, h, dv[j].y * xv[j].y * bv[j].y); ap *= a;
                a = __expf(dv[j].x * A); h = fmaf(a, h, dv[j].x * xv[j].x * bv[j].x); ap *= a;
            }
        }
    }
    size_t o = ((size_t)(dir * NCH + c) << 11) + (size_t)bxd * 256 + tid;
    cA[o] = ap;
    cB[o] = h;
}

// ---------------- scan pass 1.5: serial prefix over chunk carries ----------------
__global__ void __launch_bounds__(256) k_scan2p(
        const float* __restrict__ cA, const float* __restrict__ cB,
        float* __restrict__ Hinit) {
    int idx = blockIdx.x * 256 + threadIdx.x;  // 4096
    int dir = idx >> 11;
    int ds = idx & 2047;
    float h = 0.f;
    int c = 0;
    while (c < NCH) {
        int n = (NCH - c < 8) ? (NCH - c) : 8;
        float av[8], bv[8];
        for (int j = 0; j < n; j++) {
            size_t o = ((size_t)(dir * NCH + c + j) << 11) + ds;
            av[j] = cA[o];
            bv[j] = cB[o];
        }
        for (int j = 0; j < n; j++) {
            size_t o = ((size_t)(dir * NCH + c + j) << 11) + ds;
            Hinit[o] = h;
            h = fmaf(av[j], h, bv[j]);
        }
        c += n;
    }
}

// ------- scan pass 2: carry-in + register-batched replay; y via small LDS transpose -------
__global__ void __launch_bounds__(256) k_scan3s(
        const float* __restrict__ dtT, const float* __restrict__ xcT,
        const float* __restrict__ BT, const float* __restrict__ CT,
        const float* __restrict__ Alog, const float* __restrict__ Dres,
        const float* __restrict__ Hinit, float* __restrict__ y) {
    __shared__ __align__(16) float s_y[16 * YSTR];   // [dl][t]
    int bxd = blockIdx.x;
    int c   = blockIdx.y;
    int dir = blockIdx.z;
    int tid = threadIdx.x;
    int s = tid & 15, dl = tid >> 4;
    int d = bxd * 16 + dl;
    const float* dp = dtT + (size_t)(dir * 128 + d) * L_SEQ;
    const float* xp = xcT + (size_t)(dir * 128 + d) * L_SEQ;
    const float* bp = BT  + (size_t)(dir * 16 + s) * L_SEQ;
    const float* cp = CT  + (size_t)(dir * 16 + s) * L_SEQ;
    float carry = Hinit[((size_t)(dir * NCH + c) << 11) + (size_t)bxd * 256 + tid];
    float A = -expf(Alog[d * 16 + s]);
    float Dv = Dres[d];
    float h = carry;
    if (dir == 0) {
        int base = c * 64;
        for (int b = 0; b < 4; b++) {
            float4 dv[4], xv[4], bv[4], cv[4];
            #pragma unroll
            for (int j = 0; j < 4; j++) {
                int o = base + 16 * b + 4 * j;
                dv[j] = *(const float4*)&dp[o];
                xv[j] = *(const float4*)&xp[o];
                bv[j] = *(const float4*)&bp[o];
                cv[j] = *(const float4*)&cp[o];
            }
            #pragma unroll
            for (int j = 0; j < 4; j++) {
                int t = 16 * b + 4 * j;
                float a, val;
                a = __expf(dv[j].x * A); h = fmaf(a, h, dv[j].x * xv[j].x * bv[j].x);
                val = h * cv[j].x;
                val += ror16f<0x121>(val); val += ror16f<0x122>(val);
                val += ror16f<0x124>(val); val += ror16f<0x128>(val);
                if (s == 0) s_y[dl * YSTR + t + 0] = val + xv[j].x * Dv;
                a = __expf(dv[j].y * A); h = fmaf(a, h, dv[j].y * xv[j].y * bv[j].y);
                val = h * cv[j].y;
                val += ror16f<0x121>(val); val += ror16f<0x122>(val);
                val += ror16f<0x124>(val); val += ror16f<0x128>(val);
                if (s == 0) s_y[dl * YSTR + t + 1] = val + xv[j].y * Dv;
                a = __expf(dv[j].z * A); h = fmaf(a, h, dv[j].z * xv[j].z * bv[j].z);
                val = h * cv[j].z;
                val += ror16f<0x121>(val); val += ror16f<0x122>(val);
                val += ror16f<0x124>(val); val += ror16f<0x128>(val);
                if (s == 0) s_y[dl * YSTR + t + 2] = val + xv[j].z * Dv;
                a = __expf(dv[j].w * A); h = fmaf(a, h, dv[j].w * xv[j].w * bv[j].w);
                val = h * cv[j].w;
                val += ror16f<0x121>(val); val += ror16f<0x122>(val);
                val += ror16f<0x124>(val); val += ror16f<0x128>(val);
                if (s == 0) s_y[dl * YSTR + t + 3] = val + xv[j].w * Dv;
            }
        }
    } else {
        for (int b = 0; b < 4; b++) {
            float4 dv[4], xv[4], bv[4], cv[4];
            #pragma unroll
            for (int j = 0; j < 4; j++) {
                int o = L_SEQ - 64 * c - 4 - 16 * b - 4 * j;
                dv[j] = *(const float4*)&dp[o];
                xv[j] = *(const float4*)&xp[o];
                bv[j] = *(const float4*)&bp[o];
                cv[j] = *(const float4*)&cp[o];
            }
            #pragma unroll
            for (int j = 0; j < 4; j++) {
                int t = 16 * b + 4 * j;   // logical order within chunk
                float a, val;
                a = __expf(dv[j].w * A); h = fmaf(a, h, dv[j].w * xv[j].w * bv[j].w);
                val = h * cv[j].w;
                val += ror16f<0x121>(val); val += ror16f<0x122>(val);
                val += ror16f<0x124>(val); val += ror16f<0x128>(val);
                if (s == 0) s_y[dl * YSTR + t + 0] = val + xv[j].w * Dv;
                a = __expf(dv[j].z * A); h = fmaf(a, h, dv[j].z * xv[j].z * bv[j].z);
                val = h * cv[j].z;
                val += ror16f<0x121>(val); val += ror16f<0x122>(val);
                val += ror16f<0x124>(val); val += ror16f<0x128>(val);
                if (s == 0) s_y[dl * YSTR + t + 1] = val + xv[j].z * Dv;
                a = __expf(dv[j].y * A); h = fmaf(a, h, dv[j].y * xv[j].y * bv[j].y);
                val = h * cv[j].y;
                val += ror16f<0x121>(val); val += ror16f<0x122>(val);
                val += ror16f<0x124>(val); val += ror16f<0x128>(val);
                if (s == 0) s_y[dl * YSTR + t + 2] = val + xv[j].y * Dv;
                a = __expf(dv[j].x * A); h = fmaf(a, h, dv[j].x * xv[j].x * bv[j].x);
                val = h * cv[j].x;
                val += ror16f<0x121>(val); val += ror16f<0x122>(val);
                val += ror16f<0x124>(val); val += ror16f<0x128>(val);
                if (s == 0) s_y[dl * YSTR + t + 3] = val + xv[j].x * Dv;
            }
        }
    }
    __syncthreads();
    // write y row-major: lane mapping t-major for coalesced 64B segments
    {
        int dd = tid & 15, q = tid >> 4;
        int dg = bxd * 16 + dd;
        float4 v = *(const float4*)&s_y[dd * YSTR + 4 * q];
        float* yp = y + (size_t)dir * L_SEQ * 128;
        if (dir == 0) {
            int r0 = c * 64 + 4 * q;
            yp[(size_t)(r0 + 0) * 128 + dg] = v.x;
            yp[(size_t)(r0 + 1) * 128 + dg] = v.y;
            yp[(size_t)(r0 + 2) * 128 + dg] = v.z;
            yp[(size_t)(r0 + 3) * 128 + dg] = v.w;
        } else {
            int r0 = L_SEQ - 1 - (c * 64 + 4 * q);
            yp[(size_t)(r0 - 0) * 128 + dg] = v.x;
            yp[(size_t)(r0 - 1) * 128 + dg] = v.y;
            yp[(size_t)(r0 - 2) * 128 + dg] = v.z;
            yp[(size_t)(r0 - 3) * 128 + dg] = v.w;
        }
    }
}

// ------- out-GEMM + silu(z) gate + residual + layernorm + permute; 4 rows/block -------
__global__ void __launch_bounds__(256) k_outln(
        const float* __restrict__ x, const float* __restrict__ y,
        const float* __restrict__ xz, const float* __restrict__ Wout,
        const float* __restrict__ lng, const float* __restrict__ lnb,
        float* __restrict__ xnext, int permMode) {
    __shared__ __align__(16) float s_g[4][128];
    int w = threadIdx.x >> 6;
    int j = threadIdx.x & 63;
    int l = blockIdx.x * 4 + w;
    float z1 = xz[(size_t)l * 256 + 128 + j];
    float z2 = xz[(size_t)l * 256 + 192 + j];
    float sz1 = z1 / (1.f + expf(-z1));
    float sz2 = z2 / (1.f + expf(-z2));
    s_g[w][j]      = 0.5f * (y[(size_t)l * 128 + j] + y[(size_t)(L_SEQ + l) * 128 + j]) * sz1;
    s_g[w][j + 64] = 0.5f * (y[(size_t)l * 128 + 64 + j] + y[(size_t)(L_SEQ + l) * 128 + 64 + j]) * sz2;
    __syncthreads();
    float acc = x[(size_t)l * 64 + j];
    for (int i = 0; i < 128; i += 4) {
        float4 gv = *(const float4*)&s_g[w][i];
        acc = fmaf(gv.x, Wout[(i + 0) * 64 + j], acc);
        acc = fmaf(gv.y, Wout[(i + 1) * 64 + j], acc);
        acc = fmaf(gv.z, Wout[(i + 2) * 64 + j], acc);
        acc = fmaf(gv.w, Wout[(i + 3) * 64 + j], acc);
    }
    float m = acc;
    for (int o = 32; o >= 1; o >>= 1) m += __shfl_xor(m, o);
    m *= (1.f / 64.f);
    float dv = acc - m;
    float v = dv * dv;
    for (int o = 32; o >= 1; o >>= 1) v += __shfl_xor(v, o);
    v *= (1.f / 64.f);
    float out = dv * rsqrtf(v + 1e-5f) * lng[j] + lnb[j];
    int l2;
    if (permMode == 0) l2 = (l % 64) * 101 + (l / 64);   // (s,c)->(c,s)
    else               l2 = (l % 101) * 64 + (l / 101);  // (c,s)->(s,c)
    xnext[(size_t)l2 * 64 + j] = out;
}

// ---------------- epilogue ----------------
__global__ void k_epilogue(const float* __restrict__ x, const float* __restrict__ Wfc,
                           const float* __restrict__ bfc, const float* __restrict__ ytrue,
                           const int* __restrict__ halfwin, const int* __restrict__ rows,
                           float* __restrict__ out) {
    int k = threadIdx.x;  // 64
    int hw = halfwin[0];
    int c = rows[k];
    const float* xr = x + ((size_t)hw * 64 + c) * 64;
    float acc = bfc[0];
    for (int i = 0; i < 64; i++) acc += xr[i] * Wfc[i];
    float s = 1.f / (1.f + expf(-acc));
    float r = 1.f - fabsf(ytrue[k] - s);
    out[k] = r;
}

extern "C" void kernel_launch(void* const* d_in, const int* in_sizes, int n_in,
                              void* d_out, int out_size, void* d_ws, size_t ws_size,
                              hipStream_t stream) {
    const float* DNA   = (const float*)d_in[0];
    const float* CpG   = (const float*)d_in[1];
    const float* cel   = (const float*)d_in[2];
    const float* pos   = (const float*)d_in[3];
    const float* ytrue = (const float*)d_in[4];
    const float* Wfcc  = (const float*)d_in[5];
    const float* bfcc  = (const float*)d_in[6];
    const float* Win   = (const float*)d_in[7];
    const float* convw = (const float*)d_in[8];
    const float* convb = (const float*)d_in[9];
    const float* Wxp   = (const float*)d_in[10];
    const float* Wdt   = (const float*)d_in[11];
    const float* bdt   = (const float*)d_in[12];
    const float* Alog  = (const float*)d_in[13];
    const float* Dres  = (const float*)d_in[14];
    const float* Wout  = (const float*)d_in[15];
    const float* lng   = (const float*)d_in[16];
    const float* lnb   = (const float*)d_in[17];
    const float* Wfc   = (const float*)d_in[18];
    const float* bfc   = (const float*)d_in[19];
    const int* halfwin = (const int*)d_in[20];
    const int* rows    = (const int*)d_in[21];

    float* ws = (float*)d_ws;
    size_t off = 0;
    float* x0  = ws + off; off += (size_t)L_SEQ * 64;
    float* x1  = ws + off; off += (size_t)L_SEQ * 64;
    float* xz  = ws + off; off += (size_t)L_SEQ * 256;
    float* dtT = ws + off; off += (size_t)2 * 128 * L_SEQ;
    float* xcT = ws + off; off += (size_t)2 * 128 * L_SEQ;
    float* BT  = ws + off; off += (size_t)2 * 16 * L_SEQ;
    float* CT  = ws + off; off += (size_t)2 * 16 * L_SEQ;
    float* y   = ws + off; off += (size_t)2 * L_SEQ * 128;
    float* cA  = ws + off; off += (size_t)2 * NCH * 2048;
    float* cB  = ws + off; off += (size_t)2 * NCH * 2048;
    float* Hi  = ws + off; off += (size_t)2 * NCH * 2048;

    k_embed<<<L_SEQ, 64, 0, stream>>>(DNA, CpG, cel, pos, Wfcc, bfcc, x0);

    float* xcur = x0;
    float* xnxt = x1;
    for (int sb = 0; sb < 8; sb++) {
        k_gemm_in<<<L_SEQ / 8, 256, 0, stream>>>(xcur, Win, xz);
        k_convdt<<<L_SEQ / 16, 256, 0, stream>>>(xz, convw, convb, Wxp, Wdt, bdt,
                                                 dtT, xcT, BT, CT);
        k_scan1s<<<dim3(8, NCH, 2), 256, 0, stream>>>(dtT, xcT, BT, Alog, cA, cB);
        k_scan2p<<<16, 256, 0, stream>>>(cA, cB, Hi);
        k_scan3s<<<dim3(8, NCH, 2), 256, 0, stream>>>(dtT, xcT, BT, CT, Alog, Dres,
                                                      Hi, y);
        k_outln<<<L_SEQ / 4, 256, 0, stream>>>(xcur, y, xz, Wout, lng, lnb, xnxt,
                                               (sb % 2 == 0) ? 0 : 1);
        float* tmp = xcur; xcur = xnxt; xnxt = tmp;
    }

    k_epilogue<<<1, 64, 0, stream>>>(xcur, Wfc, bfc, ytrue, halfwin, rows, (float*)d_out);
}

// Round 8
// 989.333 us; speedup vs baseline: 1.2762x; 1.2762x over previous
//
#include <hip/hip_runtime.h>
#include <hip/hip_bf16.h>
#include <math.h>

#define L_SEQ 6464
#define DM 64
#define DI 128
#define DS 16
#define CHUNK 64
#define NCH 101   // 6464 = 101 * 64; chunk starts are 16B-aligned
#define YSTR 68   // s_y stride: 17*16B aligned, 2-way bank alias only

// ---------------- prologue: concat + pos, then @W_fcc + b_fcc ----------------
__global__ void k_embed(const float* __restrict__ DNA, const float* __restrict__ CpG,
                        const float* __restrict__ cell, const float* __restrict__ pos,
                        const float* __restrict__ Wfcc, const float* __restrict__ bfcc,
                        float* __restrict__ x0) {
    int l = blockIdx.x;
    int j = threadIdx.x;  // 64
    __shared__ float in64[64];
    float v;
    if (j < 16)       v = CpG[l * 16 + j];
    else if (j < 32)  v = cell[l * 16 + (j - 16)];
    else              v = DNA[l * 32 + (j - 32)];
    v += pos[l * 64 + j];
    in64[j] = v;
    __syncthreads();
    float acc = bfcc[j];
    for (int i = 0; i < 64; i++) acc += in64[i] * Wfcc[i * 64 + j];
    x0[(size_t)l * 64 + j] = acc;
}

// ---------------- xz = x @ W_in : 8 rows/block, f4 LDS reads ----------------
__global__ void __launch_bounds__(256) k_gemm_in(const float* __restrict__ x,
                                                 const float* __restrict__ Win,
                                                 float* __restrict__ xz) {
    __shared__ __align__(16) float s_x[8][64];
    int t0 = blockIdx.x * 8;
    int tid = threadIdx.x;
    for (int i = tid; i < 8 * 64; i += 256) {
        int rr = i >> 6, c = i & 63;
        s_x[rr][c] = x[(size_t)(t0 + rr) * 64 + c];
    }
    __syncthreads();
    int j = tid;  // 256 cols
    float acc[8];
    #pragma unroll
    for (int r = 0; r < 8; r++) acc[r] = 0.f;
    for (int i = 0; i < 64; i += 4) {
        float w0 = Win[(i + 0) * 256 + j];
        float w1 = Win[(i + 1) * 256 + j];
        float w2 = Win[(i + 2) * 256 + j];
        float w3 = Win[(i + 3) * 256 + j];
        #pragma unroll
        for (int r = 0; r < 8; r++) {
            float4 xv = *(const float4*)&s_x[r][i];
            acc[r] = fmaf(xv.x, w0, fmaf(xv.y, w1, fmaf(xv.z, w2, fmaf(xv.w, w3, acc[r]))));
        }
    }
    #pragma unroll
    for (int r = 0; r < 8; r++) xz[(size_t)(t0 + r) * 256 + j] = acc[r];
}

// ------- fused conv(+silu) both dirs + xdbl + dt/B/C -> TRANSPOSED outputs -------
__global__ void __launch_bounds__(256) k_convdt(
        const float* __restrict__ xz, const float* __restrict__ convw,
        const float* __restrict__ convb, const float* __restrict__ Wxp,
        const float* __restrict__ Wdt, const float* __restrict__ bdt,
        float* __restrict__ dtT, float* __restrict__ xcT,
        float* __restrict__ BT, float* __restrict__ CT) {
    __shared__ __align__(16) float s_xi[22][128];    // xi rows t0-3 .. t0+18
    __shared__ __align__(16) float s_xc[16][128];
    __shared__ __align__(16) float s_dtl[16][128];
    __shared__ __align__(16) float s_xd[16][36];
    __shared__ __align__(16) float s_wxpT[36 * 132]; // wxpT[t][i], stride 132 (16B-aligned)
    int t0 = blockIdx.x * 16;
    int tid = threadIdx.x;
    for (int i = tid; i < 128 * 36; i += 256) {
        int ii = i / 36, t = i - ii * 36;
        s_wxpT[t * 132 + ii] = Wxp[i];
    }
    for (int i = tid; i < 22 * 32; i += 256) {
        int rr = i >> 5, q = i & 31;
        int r = t0 - 3 + rr;
        float4 v = make_float4(0.f, 0.f, 0.f, 0.f);
        if (r >= 0 && r < L_SEQ) v = *(const float4*)&xz[(size_t)r * 256 + 4 * q];
        s_xi[rr][4 * q + 0] = v.x;
        s_xi[rr][4 * q + 1] = v.y;
        s_xi[rr][4 * q + 2] = v.z;
        s_xi[rr][4 * q + 3] = v.w;
    }
    __syncthreads();
    for (int dir = 0; dir < 2; dir++) {
        // conv + silu
        for (int i = tid; i < 16 * 128; i += 256) {
            int rr = i >> 7, d = i & 127;
            int lr = rr + 3;
            float acc = convb[d];
            if (dir == 0) {
                #pragma unroll
                for (int k = 0; k < 4; k++) acc += convw[d * 4 + k] * s_xi[lr - 3 + k][d];
            } else {
                #pragma unroll
                for (int k = 0; k < 4; k++) acc += convw[d * 4 + k] * s_xi[lr + 3 - k][d];
            }
            s_xc[rr][d] = acc / (1.f + expf(-acc));
        }
        __syncthreads();
        // xdbl = xc @ W_xp (36 cols), b128 both operands
        for (int o = tid; o < 16 * 36; o += 256) {
            int rr = o / 36, t = o - rr * 36;
            float acc = 0.f;
            for (int i = 0; i < 128; i += 4) {
                float4 xv = *(const float4*)&s_xc[rr][i];
                float4 wv = *(const float4*)&s_wxpT[t * 132 + i];
                acc += xv.x * wv.x + xv.y * wv.y + xv.z * wv.z + xv.w * wv.w;
            }
            s_xd[rr][t] = acc;
        }
        __syncthreads();
        // dt = softplus(xdbl[:, :4] @ W_dt + b_dt)
        for (int o = tid; o < 16 * 128; o += 256) {
            int rr = o >> 7, d = o & 127;
            float pre = bdt[d];
            #pragma unroll
            for (int r = 0; r < 4; r++) pre += s_xd[rr][r] * Wdt[r * 128 + d];
            s_dtl[rr][d] = (pre > 20.f) ? pre : log1pf(expf(pre));
        }
        __syncthreads();
        // transposed stores: dtT/xcT [dir][d][L]
        for (int i = tid; i < 512; i += 256) {
            int q = i >> 7, d = i & 127;
            float4 a, b;
            a.x = s_dtl[4 * q + 0][d]; a.y = s_dtl[4 * q + 1][d];
            a.z = s_dtl[4 * q + 2][d]; a.w = s_dtl[4 * q + 3][d];
            b.x = s_xc[4 * q + 0][d];  b.y = s_xc[4 * q + 1][d];
            b.z = s_xc[4 * q + 2][d];  b.w = s_xc[4 * q + 3][d];
            size_t base = (size_t)(dir * 128 + d) * L_SEQ + t0 + 4 * q;
            *(float4*)&dtT[base] = a;
            *(float4*)&xcT[base] = b;
        }
        // BT/CT [dir][s][L]
        if (tid < 128) {
            int cc = tid >> 2, q = tid & 3;
            float4 v;
            v.x = s_xd[4 * q + 0][4 + cc]; v.y = s_xd[4 * q + 1][4 + cc];
            v.z = s_xd[4 * q + 2][4 + cc]; v.w = s_xd[4 * q + 3][4 + cc];
            float* dst = (cc < 16) ? BT : CT;
            *(float4*)&dst[(size_t)(dir * 16 + (cc & 15)) * L_SEQ + t0 + 4 * q] = v;
        }
        __syncthreads();
    }
}

// ---------------- DPP 16-lane row rotate ----------------
template<int CTRL>
__device__ __forceinline__ float ror16f(float v) {
    return __int_as_float(__builtin_amdgcn_update_dpp(0, __float_as_int(v), CTRL, 0xf, 0xf, true));
}

// ---------------- scan pass 1: dbuf register-batched per-chunk (a_prod, h_end) ----------------
template<int DIR>
__device__ __forceinline__ void scan1_body(
        const float* __restrict__ dp, const float* __restrict__ xp,
        const float* __restrict__ bp, int c, float A, float& h, float& ap) {
    float4 dv[2][4], xv[2][4], bv[2][4];
    #pragma unroll
    for (int j = 0; j < 4; j++) {
        int o = DIR ? (L_SEQ - 64 * c - 4 - 4 * j) : (64 * c + 4 * j);
        dv[0][j] = *(const float4*)&dp[o];
        xv[0][j] = *(const float4*)&xp[o];
        bv[0][j] = *(const float4*)&bp[o];
    }
    #pragma unroll
    for (int b = 0; b < 4; b++) {
        const int cur = b & 1, nxt = cur ^ 1;
        if (b < 3) {
            #pragma unroll
            for (int j = 0; j < 4; j++) {
                int o = DIR ? (L_SEQ - 64 * c - 4 - 16 * (b + 1) - 4 * j)
                            : (64 * c + 16 * (b + 1) + 4 * j);
                dv[nxt][j] = *(const float4*)&dp[o];
                xv[nxt][j] = *(const float4*)&xp[o];
                bv[nxt][j] = *(const float4*)&bp[o];
            }
        }
        #pragma unroll
        for (int j = 0; j < 4; j++) {
            float a;
            if (DIR == 0) {
                a = __expf(dv[cur][j].x * A); h = fmaf(a, h, dv[cur][j].x * xv[cur][j].x * bv[cur][j].x); ap *= a;
                a = __expf(dv[cur][j].y * A); h = fmaf(a, h, dv[cur][j].y * xv[cur][j].y * bv[cur][j].y); ap *= a;
                a = __expf(dv[cur][j].z * A); h = fmaf(a, h, dv[cur][j].z * xv[cur][j].z * bv[cur][j].z); ap *= a;
                a = __expf(dv[cur][j].w * A); h = fmaf(a, h, dv[cur][j].w * xv[cur][j].w * bv[cur][j].w); ap *= a;
            } else {
                a = __expf(dv[cur][j].w * A); h = fmaf(a, h, dv[cur][j].w * xv[cur][j].w * bv[cur][j].w); ap *= a;
                a = __expf(dv[cur][j].z * A); h = fmaf(a, h, dv[cur][j].z * xv[cur][j].z * bv[cur][j].z); ap *= a;
                a = __expf(dv[cur][j].y * A); h = fmaf(a, h, dv[cur][j].y * xv[cur][j].y * bv[cur][j].y); ap *= a;
                a = __expf(dv[cur][j].x * A); h = fmaf(a, h, dv[cur][j].x * xv[cur][j].x * bv[cur][j].x); ap *= a;
            }
        }
    }
}

__global__ void __launch_bounds__(256) k_scan1s(
        const float* __restrict__ dtT, const float* __restrict__ xcT,
        const float* __restrict__ BT, const float* __restrict__ Alog,
        float* __restrict__ cA, float* __restrict__ cB) {
    int bxd = blockIdx.x;   // d-group (8)
    int c   = blockIdx.y;   // chunk (101)
    int dir = blockIdx.z;   // 2
    int tid = threadIdx.x;
    int s = tid & 15, dl = tid >> 4;
    int d = bxd * 16 + dl;
    const float* dp = dtT + (size_t)(dir * 128 + d) * L_SEQ;
    const float* xp = xcT + (size_t)(dir * 128 + d) * L_SEQ;
    const float* bp = BT  + (size_t)(dir * 16 + s) * L_SEQ;
    float A = -expf(Alog[d * 16 + s]);
    float h = 0.f, ap = 1.f;
    if (dir == 0) scan1_body<0>(dp, xp, bp, c, A, h, ap);
    else          scan1_body<1>(dp, xp, bp, c, A, h, ap);
    size_t o = ((size_t)(dir * NCH + c) << 11) + (size_t)bxd * 256 + tid;
    cA[o] = ap;
    cB[o] = h;
}

// ---------------- scan pass 1.5: serial prefix, compile-time unrolled batches ----------------
__global__ void __launch_bounds__(256) k_scan2p(
        const float* __restrict__ cA, const float* __restrict__ cB,
        float* __restrict__ Hinit) {
    int idx = blockIdx.x * 256 + threadIdx.x;  // 4096
    int dir = idx >> 11;
    int ds = idx & 2047;
    size_t base = ((size_t)(dir * NCH) << 11) + ds;
    float h = 0.f;
    #pragma unroll 1
    for (int b = 0; b < 12; b++) {   // 12 * 8 = 96
        float av[8], bv[8];
        #pragma unroll
        for (int j = 0; j < 8; j++) {
            size_t o = base + ((size_t)(b * 8 + j) << 11);
            av[j] = cA[o];
            bv[j] = cB[o];
        }
        #pragma unroll
        for (int j = 0; j < 8; j++) {
            size_t o = base + ((size_t)(b * 8 + j) << 11);
            Hinit[o] = h;
            h = fmaf(av[j], h, bv[j]);
        }
    }
    {   // tail: 96..100
        float av[5], bv[5];
        #pragma unroll
        for (int j = 0; j < 5; j++) {
            size_t o = base + ((size_t)(96 + j) << 11);
            av[j] = cA[o];
            bv[j] = cB[o];
        }
        #pragma unroll
        for (int j = 0; j < 5; j++) {
            size_t o = base + ((size_t)(96 + j) << 11);
            Hinit[o] = h;
            h = fmaf(av[j], h, bv[j]);
        }
    }
}

// ------- scan pass 2: carry-in + dbuf register replay; y via small LDS transpose -------
#define S3STEP(COMP, K)                                                            \
    {                                                                              \
        float a = __expf(dv[cur][j].COMP * A);                                     \
        h = fmaf(a, h, dv[cur][j].COMP * xv[cur][j].COMP * bv[cur][j].COMP);       \
        float val = h * cv[cur][j].COMP;                                           \
        val += ror16f<0x121>(val); val += ror16f<0x122>(val);                      \
        val += ror16f<0x124>(val); val += ror16f<0x128>(val);                      \
        if (s == 0) s_y[dl * YSTR + 16 * b + 4 * j + K] = val + xv[cur][j].COMP * Dv; \
    }

template<int DIR>
__device__ __forceinline__ void scan3_body(
        const float* __restrict__ dp, const float* __restrict__ xp,
        const float* __restrict__ bp, const float* __restrict__ cp,
        int c, float A, float Dv, int s, int dl, float* __restrict__ s_y, float h) {
    float4 dv[2][4], xv[2][4], bv[2][4], cv[2][4];
    #pragma unroll
    for (int j = 0; j < 4; j++) {
        int o = DIR ? (L_SEQ - 64 * c - 4 - 4 * j) : (64 * c + 4 * j);
        dv[0][j] = *(const float4*)&dp[o];
        xv[0][j] = *(const float4*)&xp[o];
        bv[0][j] = *(const float4*)&bp[o];
        cv[0][j] = *(const float4*)&cp[o];
    }
    #pragma unroll
    for (int b = 0; b < 4; b++) {
        const int cur = b & 1, nxt = cur ^ 1;
        if (b < 3) {
            #pragma unroll
            for (int j = 0; j < 4; j++) {
                int o = DIR ? (L_SEQ - 64 * c - 4 - 16 * (b + 1) - 4 * j)
                            : (64 * c + 16 * (b + 1) + 4 * j);
                dv[nxt][j] = *(const float4*)&dp[o];
                xv[nxt][j] = *(const float4*)&xp[o];
                bv[nxt][j] = *(const float4*)&bp[o];
                cv[nxt][j] = *(const float4*)&cp[o];
            }
        }
        #pragma unroll
        for (int j = 0; j < 4; j++) {
            if (DIR == 0) {
                S3STEP(x, 0) S3STEP(y, 1) S3STEP(z, 2) S3STEP(w, 3)
            } else {
                S3STEP(w, 0) S3STEP(z, 1) S3STEP(y, 2) S3STEP(x, 3)
            }
        }
    }
}

__global__ void __launch_bounds__(256) k_scan3s(
        const float* __restrict__ dtT, const float* __restrict__ xcT,
        const float* __restrict__ BT, const float* __restrict__ CT,
        const float* __restrict__ Alog, const float* __restrict__ Dres,
        const float* __restrict__ Hinit, float* __restrict__ y) {
    __shared__ __align__(16) float s_y[16 * YSTR];   // [dl][t]
    int bxd = blockIdx.x;
    int c   = blockIdx.y;
    int dir = blockIdx.z;
    int tid = threadIdx.x;
    int s = tid & 15, dl = tid >> 4;
    int d = bxd * 16 + dl;
    const float* dp = dtT + (size_t)(dir * 128 + d) * L_SEQ;
    const float* xp = xcT + (size_t)(dir * 128 + d) * L_SEQ;
    const float* bp = BT  + (size_t)(dir * 16 + s) * L_SEQ;
    const float* cp = CT  + (size_t)(dir * 16 + s) * L_SEQ;
    float carry = Hinit[((size_t)(dir * NCH + c) << 11) + (size_t)bxd * 256 + tid];
    float A = -expf(Alog[d * 16 + s]);
    float Dv = Dres[d];
    if (dir == 0) scan3_body<0>(dp, xp, bp, cp, c, A, Dv, s, dl, s_y, carry);
    else          scan3_body<1>(dp, xp, bp, cp, c, A, Dv, s, dl, s_y, carry);
    __syncthreads();
    // write y row-major: lane mapping t-major for coalesced 64B segments
    {
        int dd = tid & 15, q = tid >> 4;
        int dg = bxd * 16 + dd;
        float4 v = *(const float4*)&s_y[dd * YSTR + 4 * q];
        float* yp = y + (size_t)dir * L_SEQ * 128;
        if (dir == 0) {
            int r0 = c * 64 + 4 * q;
            yp[(size_t)(r0 + 0) * 128 + dg] = v.x;
            yp[(size_t)(r0 + 1) * 128 + dg] = v.y;
            yp[(size_t)(r0 + 2) * 128 + dg] = v.z;
            yp[(size_t)(r0 + 3) * 128 + dg] = v.w;
        } else {
            int r0 = L_SEQ - 1 - (c * 64 + 4 * q);
            yp[(size_t)(r0 - 0) * 128 + dg] = v.x;
            yp[(size_t)(r0 - 1) * 128 + dg] = v.y;
            yp[(size_t)(r0 - 2) * 128 + dg] = v.z;
            yp[(size_t)(r0 - 3) * 128 + dg] = v.w;
        }
    }
}

// ------- out-GEMM + silu(z) gate + residual + layernorm + permute; 4 rows/block -------
__global__ void __launch_bounds__(256) k_outln(
        const float* __restrict__ x, const float* __restrict__ y,
        const float* __restrict__ xz, const float* __restrict__ Wout,
        const float* __restrict__ lng, const float* __restrict__ lnb,
        float* __restrict__ xnext, int permMode) {
    __shared__ __align__(16) float s_g[4][128];
    int w = threadIdx.x >> 6;
    int j = threadIdx.x & 63;
    int l = blockIdx.x * 4 + w;
    float z1 = xz[(size_t)l * 256 + 128 + j];
    float z2 = xz[(size_t)l * 256 + 192 + j];
    float sz1 = z1 / (1.f + expf(-z1));
    float sz2 = z2 / (1.f + expf(-z2));
    s_g[w][j]      = 0.5f * (y[(size_t)l * 128 + j] + y[(size_t)(L_SEQ + l) * 128 + j]) * sz1;
    s_g[w][j + 64] = 0.5f * (y[(size_t)l * 128 + 64 + j] + y[(size_t)(L_SEQ + l) * 128 + 64 + j]) * sz2;
    __syncthreads();
    float acc = x[(size_t)l * 64 + j];
    for (int i = 0; i < 128; i += 4) {
        float4 gv = *(const float4*)&s_g[w][i];
        acc = fmaf(gv.x, Wout[(i + 0) * 64 + j], acc);
        acc = fmaf(gv.y, Wout[(i + 1) * 64 + j], acc);
        acc = fmaf(gv.z, Wout[(i + 2) * 64 + j], acc);
        acc = fmaf(gv.w, Wout[(i + 3) * 64 + j], acc);
    }
    float m = acc;
    for (int o = 32; o >= 1; o >>= 1) m += __shfl_xor(m, o);
    m *= (1.f / 64.f);
    float dv = acc - m;
    float v = dv * dv;
    for (int o = 32; o >= 1; o >>= 1) v += __shfl_xor(v, o);
    v *= (1.f / 64.f);
    float out = dv * rsqrtf(v + 1e-5f) * lng[j] + lnb[j];
    int l2;
    if (permMode == 0) l2 = (l % 64) * 101 + (l / 64);   // (s,c)->(c,s)
    else               l2 = (l % 101) * 64 + (l / 101);  // (c,s)->(s,c)
    xnext[(size_t)l2 * 64 + j] = out;
}

// ---------------- epilogue ----------------
__global__ void k_epilogue(const float* __restrict__ x, const float* __restrict__ Wfc,
                           const float* __restrict__ bfc, const float* __restrict__ ytrue,
                           const int* __restrict__ halfwin, const int* __restrict__ rows,
                           float* __restrict__ out) {
    int k = threadIdx.x;  // 64
    int hw = halfwin[0];
    int c = rows[k];
    const float* xr = x + ((size_t)hw * 64 + c) * 64;
    float acc = bfc[0];
    for (int i = 0; i < 64; i++) acc += xr[i] * Wfc[i];
    float s = 1.f / (1.f + expf(-acc));
    float r = 1.f - fabsf(ytrue[k] - s);
    out[k] = r;
}

extern "C" void kernel_launch(void* const* d_in, const int* in_sizes, int n_in,
                              void* d_out, int out_size, void* d_ws, size_t ws_size,
                              hipStream_t stream) {
    const float* DNA   = (const float*)d_in[0];
    const float* CpG   = (const float*)d_in[1];
    const float* cel   = (const float*)d_in[2];
    const float* pos   = (const float*)d_in[3];
    const float* ytrue = (const float*)d_in[4];
    const float* Wfcc  = (const float*)d_in[5];
    const float* bfcc  = (const float*)d_in[6];
    const float* Win   = (const float*)d_in[7];
    const float* convw = (const float*)d_in[8];
    const float* convb = (const float*)d_in[9];
    const float* Wxp   = (const float*)d_in[10];
    const float* Wdt   = (const float*)d_in[11];
    const float* bdt   = (const float*)d_in[12];
    const float* Alog  = (const float*)d_in[13];
    const float* Dres  = (const float*)d_in[14];
    const float* Wout  = (const float*)d_in[15];
    const float* lng   = (const float*)d_in[16];
    const float* lnb   = (const float*)d_in[17];
    const float* Wfc   = (const float*)d_in[18];
    const float* bfc   = (const float*)d_in[19];
    const int* halfwin = (const int*)d_in[20];
    const int* rows    = (const int*)d_in[21];

    float* ws = (float*)d_ws;
    size_t off = 0;
    float* x0  = ws + off; off += (size_t)L_SEQ * 64;
    float* x1  = ws + off; off += (size_t)L_SEQ * 64;
    float* xz  = ws + off; off += (size_t)L_SEQ * 256;
    float* dtT = ws + off; off += (size_t)2 * 128 * L_SEQ;
    float* xcT = ws + off; off += (size_t)2 * 128 * L_SEQ;
    float* BT  = ws + off; off += (size_t)2 * 16 * L_SEQ;
    float* CT  = ws + off; off += (size_t)2 * 16 * L_SEQ;
    float* y   = ws + off; off += (size_t)2 * L_SEQ * 128;
    float* cA  = ws + off; off += (size_t)2 * NCH * 2048;
    float* cB  = ws + off; off += (size_t)2 * NCH * 2048;
    float* Hi  = ws + off; off += (size_t)2 * NCH * 2048;

    k_embed<<<L_SEQ, 64, 0, stream>>>(DNA, CpG, cel, pos, Wfcc, bfcc, x0);

    float* xcur = x0;
    float* xnxt = x1;
    for (int sb = 0; sb < 8; sb++) {
        k_gemm_in<<<L_SEQ / 8, 256, 0, stream>>>(xcur, Win, xz);
        k_convdt<<<L_SEQ / 16, 256, 0, stream>>>(xz, convw, convb, Wxp, Wdt, bdt,
                                                 dtT, xcT, BT, CT);
        k_scan1s<<<dim3(8, NCH, 2), 256, 0, stream>>>(dtT, xcT, BT, Alog, cA, cB);
        k_scan2p<<<16, 256, 0, stream>>>(cA, cB, Hi);
        k_scan3s<<<dim3(8, NCH, 2), 256, 0, stream>>>(dtT, xcT, BT, CT, Alog, Dres,
                                                      Hi, y);
        k_outln<<<L_SEQ / 4, 256, 0, stream>>>(xcur, y, xz, Wout, lng, lnb, xnxt,
                                               (sb % 2 == 0) ? 0 : 1);
        float* tmp = xcur; xcur = xnxt; xnxt = tmp;
    }

    k_epilogue<<<1, 64, 0, stream>>>(xcur, Wfc, bfc, ytrue, halfwin, rows, (float*)d_out);
}

// Round 9
// 986.444 us; speedup vs baseline: 1.2799x; 1.0029x over previous
//
#include <hip/hip_runtime.h>
#include <hip/hip_bf16.h>
#include <math.h>

#define L_SEQ 6464
#define DM 64
#define DI 128
#define DS 16
#define CHUNK 64
#define NCH 101   // 6464 = 101 * 64; chunk starts are 16B-aligned
#define YSTR 68   // s_y stride: 17*16B aligned, 2-way bank alias only

// ---------------- prologue: concat + pos, then @W_fcc + b_fcc ----------------
__global__ void k_embed(const float* __restrict__ DNA, const float* __restrict__ CpG,
                        const float* __restrict__ cell, const float* __restrict__ pos,
                        const float* __restrict__ Wfcc, const float* __restrict__ bfcc,
                        float* __restrict__ x0) {
    int l = blockIdx.x;
    int j = threadIdx.x;  // 64
    __shared__ float in64[64];
    float v;
    if (j < 16)       v = CpG[l * 16 + j];
    else if (j < 32)  v = cell[l * 16 + (j - 16)];
    else              v = DNA[l * 32 + (j - 32)];
    v += pos[l * 64 + j];
    in64[j] = v;
    __syncthreads();
    float acc = bfcc[j];
    for (int i = 0; i < 64; i++) acc += in64[i] * Wfcc[i * 64 + j];
    x0[(size_t)l * 64 + j] = acc;
}

// ---------------- xz = x @ W_in : 8 rows/block, f4 LDS reads ----------------
__global__ void __launch_bounds__(256) k_gemm_in(const float* __restrict__ x,
                                                 const float* __restrict__ Win,
                                                 float* __restrict__ xz) {
    __shared__ __align__(16) float s_x[8][64];
    int t0 = blockIdx.x * 8;
    int tid = threadIdx.x;
    for (int i = tid; i < 8 * 64; i += 256) {
        int rr = i >> 6, c = i & 63;
        s_x[rr][c] = x[(size_t)(t0 + rr) * 64 + c];
    }
    __syncthreads();
    int j = tid;  // 256 cols
    float acc[8];
    #pragma unroll
    for (int r = 0; r < 8; r++) acc[r] = 0.f;
    for (int i = 0; i < 64; i += 4) {
        float w0 = Win[(i + 0) * 256 + j];
        float w1 = Win[(i + 1) * 256 + j];
        float w2 = Win[(i + 2) * 256 + j];
        float w3 = Win[(i + 3) * 256 + j];
        #pragma unroll
        for (int r = 0; r < 8; r++) {
            float4 xv = *(const float4*)&s_x[r][i];
            acc[r] = fmaf(xv.x, w0, fmaf(xv.y, w1, fmaf(xv.z, w2, fmaf(xv.w, w3, acc[r]))));
        }
    }
    #pragma unroll
    for (int r = 0; r < 8; r++) xz[(size_t)(t0 + r) * 256 + j] = acc[r];
}

// ------- fused conv(+silu) both dirs + xdbl + dt/B/C -> TRANSPOSED outputs -------
__global__ void __launch_bounds__(256) k_convdt(
        const float* __restrict__ xz, const float* __restrict__ convw,
        const float* __restrict__ convb, const float* __restrict__ Wxp,
        const float* __restrict__ Wdt, const float* __restrict__ bdt,
        float* __restrict__ dtT, float* __restrict__ xcT,
        float* __restrict__ BT, float* __restrict__ CT) {
    __shared__ __align__(16) float s_xi[22][128];    // xi rows t0-3 .. t0+18
    __shared__ __align__(16) float s_xc[16][128];
    __shared__ __align__(16) float s_dtl[16][128];
    __shared__ __align__(16) float s_xd[16][36];
    __shared__ __align__(16) float s_wxpT[36 * 132]; // wxpT[t][i], stride 132 (16B-aligned)
    int t0 = blockIdx.x * 16;
    int tid = threadIdx.x;
    for (int i = tid; i < 128 * 36; i += 256) {
        int ii = i / 36, t = i - ii * 36;
        s_wxpT[t * 132 + ii] = Wxp[i];
    }
    for (int i = tid; i < 22 * 32; i += 256) {
        int rr = i >> 5, q = i & 31;
        int r = t0 - 3 + rr;
        float4 v = make_float4(0.f, 0.f, 0.f, 0.f);
        if (r >= 0 && r < L_SEQ) v = *(const float4*)&xz[(size_t)r * 256 + 4 * q];
        s_xi[rr][4 * q + 0] = v.x;
        s_xi[rr][4 * q + 1] = v.y;
        s_xi[rr][4 * q + 2] = v.z;
        s_xi[rr][4 * q + 3] = v.w;
    }
    __syncthreads();
    for (int dir = 0; dir < 2; dir++) {
        // conv + silu
        for (int i = tid; i < 16 * 128; i += 256) {
            int rr = i >> 7, d = i & 127;
            int lr = rr + 3;
            float acc = convb[d];
            if (dir == 0) {
                #pragma unroll
                for (int k = 0; k < 4; k++) acc += convw[d * 4 + k] * s_xi[lr - 3 + k][d];
            } else {
                #pragma unroll
                for (int k = 0; k < 4; k++) acc += convw[d * 4 + k] * s_xi[lr + 3 - k][d];
            }
            s_xc[rr][d] = acc / (1.f + expf(-acc));
        }
        __syncthreads();
        // xdbl = xc @ W_xp (36 cols), b128 both operands
        for (int o = tid; o < 16 * 36; o += 256) {
            int rr = o / 36, t = o - rr * 36;
            float acc = 0.f;
            for (int i = 0; i < 128; i += 4) {
                float4 xv = *(const float4*)&s_xc[rr][i];
                float4 wv = *(const float4*)&s_wxpT[t * 132 + i];
                acc += xv.x * wv.x + xv.y * wv.y + xv.z * wv.z + xv.w * wv.w;
            }
            s_xd[rr][t] = acc;
        }
        __syncthreads();
        // dt = softplus(xdbl[:, :4] @ W_dt + b_dt)
        for (int o = tid; o < 16 * 128; o += 256) {
            int rr = o >> 7, d = o & 127;
            float pre = bdt[d];
            #pragma unroll
            for (int r = 0; r < 4; r++) pre += s_xd[rr][r] * Wdt[r * 128 + d];
            s_dtl[rr][d] = (pre > 20.f) ? pre : log1pf(expf(pre));
        }
        __syncthreads();
        // transposed stores: dtT/xcT [dir][d][L]
        for (int i = tid; i < 512; i += 256) {
            int q = i >> 7, d = i & 127;
            float4 a, b;
            a.x = s_dtl[4 * q + 0][d]; a.y = s_dtl[4 * q + 1][d];
            a.z = s_dtl[4 * q + 2][d]; a.w = s_dtl[4 * q + 3][d];
            b.x = s_xc[4 * q + 0][d];  b.y = s_xc[4 * q + 1][d];
            b.z = s_xc[4 * q + 2][d];  b.w = s_xc[4 * q + 3][d];
            size_t base = (size_t)(dir * 128 + d) * L_SEQ + t0 + 4 * q;
            *(float4*)&dtT[base] = a;
            *(float4*)&xcT[base] = b;
        }
        // BT/CT [dir][s][L]
        if (tid < 128) {
            int cc = tid >> 2, q = tid & 3;
            float4 v;
            v.x = s_xd[4 * q + 0][4 + cc]; v.y = s_xd[4 * q + 1][4 + cc];
            v.z = s_xd[4 * q + 2][4 + cc]; v.w = s_xd[4 * q + 3][4 + cc];
            float* dst = (cc < 16) ? BT : CT;
            *(float4*)&dst[(size_t)(dir * 16 + (cc & 15)) * L_SEQ + t0 + 4 * q] = v;
        }
        __syncthreads();
    }
}

// ---------------- DPP 16-lane row rotate ----------------
template<int CTRL>
__device__ __forceinline__ float ror16f(float v) {
    return __int_as_float(__builtin_amdgcn_update_dpp(0, __float_as_int(v), CTRL, 0xf, 0xf, true));
}

// ---------------- scan pass 1: dbuf register-batched per-chunk (a_prod, h_end) ----------------
template<int DIR>
__device__ __forceinline__ void scan1_body(
        const float* __restrict__ dp, const float* __restrict__ xp,
        const float* __restrict__ bp, int c, float A, float& h, float& ap) {
    float4 dv[2][4], xv[2][4], bv[2][4];
    #pragma unroll
    for (int j = 0; j < 4; j++) {
        int o = DIR ? (L_SEQ - 64 * c - 4 - 4 * j) : (64 * c + 4 * j);
        dv[0][j] = *(const float4*)&dp[o];
        xv[0][j] = *(const float4*)&xp[o];
        bv[0][j] = *(const float4*)&bp[o];
    }
    #pragma unroll
    for (int b = 0; b < 4; b++) {
        const int cur = b & 1, nxt = cur ^ 1;
        if (b < 3) {
            #pragma unroll
            for (int j = 0; j < 4; j++) {
                int o = DIR ? (L_SEQ - 64 * c - 4 - 16 * (b + 1) - 4 * j)
                            : (64 * c + 16 * (b + 1) + 4 * j);
                dv[nxt][j] = *(const float4*)&dp[o];
                xv[nxt][j] = *(const float4*)&xp[o];
                bv[nxt][j] = *(const float4*)&bp[o];
            }
        }
        // pin: prefetch for b+1 stays ABOVE compute of b (no sinking past here)
        __builtin_amdgcn_sched_barrier(0);
        #pragma unroll
        for (int j = 0; j < 4; j++) {
            float a;
            if (DIR == 0) {
                a = __expf(dv[cur][j].x * A); h = fmaf(a, h, dv[cur][j].x * xv[cur][j].x * bv[cur][j].x); ap *= a;
                a = __expf(dv[cur][j].y * A); h = fmaf(a, h, dv[cur][j].y * xv[cur][j].y * bv[cur][j].y); ap *= a;
                a = __expf(dv[cur][j].z * A); h = fmaf(a, h, dv[cur][j].z * xv[cur][j].z * bv[cur][j].z); ap *= a;
                a = __expf(dv[cur][j].w * A); h = fmaf(a, h, dv[cur][j].w * xv[cur][j].w * bv[cur][j].w); ap *= a;
            } else {
                a = __expf(dv[cur][j].w * A); h = fmaf(a, h, dv[cur][j].w * xv[cur][j].w * bv[cur][j].w); ap *= a;
                a = __expf(dv[cur][j].z * A); h = fmaf(a, h, dv[cur][j].z * xv[cur][j].z * bv[cur][j].z); ap *= a;
                a = __expf(dv[cur][j].y * A); h = fmaf(a, h, dv[cur][j].y * xv[cur][j].y * bv[cur][j].y); ap *= a;
                a = __expf(dv[cur][j].x * A); h = fmaf(a, h, dv[cur][j].x * xv[cur][j].x * bv[cur][j].x); ap *= a;
            }
        }
        __builtin_amdgcn_sched_barrier(0);
    }
}

__global__ void __launch_bounds__(256, 1) k_scan1s(
        const float* __restrict__ dtT, const float* __restrict__ xcT,
        const float* __restrict__ BT, const float* __restrict__ Alog,
        float* __restrict__ cA, float* __restrict__ cB) {
    int bxd = blockIdx.x;   // d-group (8)
    int c   = blockIdx.y;   // chunk (101)
    int dir = blockIdx.z;   // 2
    int tid = threadIdx.x;
    int s = tid & 15, dl = tid >> 4;
    int d = bxd * 16 + dl;
    const float* dp = dtT + (size_t)(dir * 128 + d) * L_SEQ;
    const float* xp = xcT + (size_t)(dir * 128 + d) * L_SEQ;
    const float* bp = BT  + (size_t)(dir * 16 + s) * L_SEQ;
    float A = -expf(Alog[d * 16 + s]);
    float h = 0.f, ap = 1.f;
    if (dir == 0) scan1_body<0>(dp, xp, bp, c, A, h, ap);
    else          scan1_body<1>(dp, xp, bp, c, A, h, ap);
    size_t o = ((size_t)(dir * NCH + c) << 11) + (size_t)bxd * 256 + tid;
    cA[o] = ap;
    cB[o] = h;
}

// ---------------- scan pass 1.5: serial prefix, compile-time unrolled batches ----------------
__global__ void __launch_bounds__(256) k_scan2p(
        const float* __restrict__ cA, const float* __restrict__ cB,
        float* __restrict__ Hinit) {
    int idx = blockIdx.x * 256 + threadIdx.x;  // 4096
    int dir = idx >> 11;
    int ds = idx & 2047;
    size_t base = ((size_t)(dir * NCH) << 11) + ds;
    float h = 0.f;
    #pragma unroll 1
    for (int b = 0; b < 12; b++) {   // 12 * 8 = 96
        float av[8], bv[8];
        #pragma unroll
        for (int j = 0; j < 8; j++) {
            size_t o = base + ((size_t)(b * 8 + j) << 11);
            av[j] = cA[o];
            bv[j] = cB[o];
        }
        __builtin_amdgcn_sched_barrier(0);
        #pragma unroll
        for (int j = 0; j < 8; j++) {
            size_t o = base + ((size_t)(b * 8 + j) << 11);
            Hinit[o] = h;
            h = fmaf(av[j], h, bv[j]);
        }
    }
    {   // tail: 96..100
        float av[5], bv[5];
        #pragma unroll
        for (int j = 0; j < 5; j++) {
            size_t o = base + ((size_t)(96 + j) << 11);
            av[j] = cA[o];
            bv[j] = cB[o];
        }
        #pragma unroll
        for (int j = 0; j < 5; j++) {
            size_t o = base + ((size_t)(96 + j) << 11);
            Hinit[o] = h;
            h = fmaf(av[j], h, bv[j]);
        }
    }
}

// ------- scan pass 2: carry-in + dbuf register replay; y via small LDS transpose -------
#define S3STEP(COMP, K)                                                            \
    {                                                                              \
        float a = __expf(dv[cur][j].COMP * A);                                     \
        h = fmaf(a, h, dv[cur][j].COMP * xv[cur][j].COMP * bv[cur][j].COMP);       \
        float val = h * cv[cur][j].COMP;                                           \
        val += ror16f<0x121>(val); val += ror16f<0x122>(val);                      \
        val += ror16f<0x124>(val); val += ror16f<0x128>(val);                      \
        if (s == 0) s_y[dl * YSTR + 16 * b + 4 * j + K] = val + xv[cur][j].COMP * Dv; \
    }

template<int DIR>
__device__ __forceinline__ void scan3_body(
        const float* __restrict__ dp, const float* __restrict__ xp,
        const float* __restrict__ bp, const float* __restrict__ cp,
        int c, float A, float Dv, int s, int dl, float* __restrict__ s_y, float h) {
    float4 dv[2][4], xv[2][4], bv[2][4], cv[2][4];
    #pragma unroll
    for (int j = 0; j < 4; j++) {
        int o = DIR ? (L_SEQ - 64 * c - 4 - 4 * j) : (64 * c + 4 * j);
        dv[0][j] = *(const float4*)&dp[o];
        xv[0][j] = *(const float4*)&xp[o];
        bv[0][j] = *(const float4*)&bp[o];
        cv[0][j] = *(const float4*)&cp[o];
    }
    #pragma unroll
    for (int b = 0; b < 4; b++) {
        const int cur = b & 1, nxt = cur ^ 1;
        if (b < 3) {
            #pragma unroll
            for (int j = 0; j < 4; j++) {
                int o = DIR ? (L_SEQ - 64 * c - 4 - 16 * (b + 1) - 4 * j)
                            : (64 * c + 16 * (b + 1) + 4 * j);
                dv[nxt][j] = *(const float4*)&dp[o];
                xv[nxt][j] = *(const float4*)&xp[o];
                bv[nxt][j] = *(const float4*)&bp[o];
                cv[nxt][j] = *(const float4*)&cp[o];
            }
        }
        // pin: prefetch for b+1 stays ABOVE compute of b (no sinking past here)
        __builtin_amdgcn_sched_barrier(0);
        #pragma unroll
        for (int j = 0; j < 4; j++) {
            if (DIR == 0) {
                S3STEP(x, 0) S3STEP(y, 1) S3STEP(z, 2) S3STEP(w, 3)
            } else {
                S3STEP(w, 0) S3STEP(z, 1) S3STEP(y, 2) S3STEP(x, 3)
            }
        }
        __builtin_amdgcn_sched_barrier(0);
    }
}

__global__ void __launch_bounds__(256, 1) k_scan3s(
        const float* __restrict__ dtT, const float* __restrict__ xcT,
        const float* __restrict__ BT, const float* __restrict__ CT,
        const float* __restrict__ Alog, const float* __restrict__ Dres,
        const float* __restrict__ Hinit, float* __restrict__ y) {
    __shared__ __align__(16) float s_y[16 * YSTR];   // [dl][t]
    int bxd = blockIdx.x;
    int c   = blockIdx.y;
    int dir = blockIdx.z;
    int tid = threadIdx.x;
    int s = tid & 15, dl = tid >> 4;
    int d = bxd * 16 + dl;
    const float* dp = dtT + (size_t)(dir * 128 + d) * L_SEQ;
    const float* xp = xcT + (size_t)(dir * 128 + d) * L_SEQ;
    const float* bp = BT  + (size_t)(dir * 16 + s) * L_SEQ;
    const float* cp = CT  + (size_t)(dir * 16 + s) * L_SEQ;
    float carry = Hinit[((size_t)(dir * NCH + c) << 11) + (size_t)bxd * 256 + tid];
    float A = -expf(Alog[d * 16 + s]);
    float Dv = Dres[d];
    if (dir == 0) scan3_body<0>(dp, xp, bp, cp, c, A, Dv, s, dl, s_y, carry);
    else          scan3_body<1>(dp, xp, bp, cp, c, A, Dv, s, dl, s_y, carry);
    __syncthreads();
    // write y row-major: lane mapping t-major for coalesced 64B segments
    {
        int dd = tid & 15, q = tid >> 4;
        int dg = bxd * 16 + dd;
        float4 v = *(const float4*)&s_y[dd * YSTR + 4 * q];
        float* yp = y + (size_t)dir * L_SEQ * 128;
        if (dir == 0) {
            int r0 = c * 64 + 4 * q;
            yp[(size_t)(r0 + 0) * 128 + dg] = v.x;
            yp[(size_t)(r0 + 1) * 128 + dg] = v.y;
            yp[(size_t)(r0 + 2) * 128 + dg] = v.z;
            yp[(size_t)(r0 + 3) * 128 + dg] = v.w;
        } else {
            int r0 = L_SEQ - 1 - (c * 64 + 4 * q);
            yp[(size_t)(r0 - 0) * 128 + dg] = v.x;
            yp[(size_t)(r0 - 1) * 128 + dg] = v.y;
            yp[(size_t)(r0 - 2) * 128 + dg] = v.z;
            yp[(size_t)(r0 - 3) * 128 + dg] = v.w;
        }
    }
}

// ------- out-GEMM + silu(z) gate + residual + layernorm + permute; 4 rows/block -------
__global__ void __launch_bounds__(256) k_outln(
        const float* __restrict__ x, const float* __restrict__ y,
        const float* __restrict__ xz, const float* __restrict__ Wout,
        const float* __restrict__ lng, const float* __restrict__ lnb,
        float* __restrict__ xnext, int permMode) {
    __shared__ __align__(16) float s_g[4][128];
    int w = threadIdx.x >> 6;
    int j = threadIdx.x & 63;
    int l = blockIdx.x * 4 + w;
    float z1 = xz[(size_t)l * 256 + 128 + j];
    float z2 = xz[(size_t)l * 256 + 192 + j];
    float sz1 = z1 / (1.f + expf(-z1));
    float sz2 = z2 / (1.f + expf(-z2));
    s_g[w][j]      = 0.5f * (y[(size_t)l * 128 + j] + y[(size_t)(L_SEQ + l) * 128 + j]) * sz1;
    s_g[w][j + 64] = 0.5f * (y[(size_t)l * 128 + 64 + j] + y[(size_t)(L_SEQ + l) * 128 + 64 + j]) * sz2;
    __syncthreads();
    float acc = x[(size_t)l * 64 + j];
    for (int i = 0; i < 128; i += 4) {
        float4 gv = *(const float4*)&s_g[w][i];
        acc = fmaf(gv.x, Wout[(i + 0) * 64 + j], acc);
        acc = fmaf(gv.y, Wout[(i + 1) * 64 + j], acc);
        acc = fmaf(gv.z, Wout[(i + 2) * 64 + j], acc);
        acc = fmaf(gv.w, Wout[(i + 3) * 64 + j], acc);
    }
    float m = acc;
    for (int o = 32; o >= 1; o >>= 1) m += __shfl_xor(m, o);
    m *= (1.f / 64.f);
    float dv = acc - m;
    float v = dv * dv;
    for (int o = 32; o >= 1; o >>= 1) v += __shfl_xor(v, o);
    v *= (1.f / 64.f);
    float out = dv * rsqrtf(v + 1e-5f) * lng[j] + lnb[j];
    int l2;
    if (permMode == 0) l2 = (l % 64) * 101 + (l / 64);   // (s,c)->(c,s)
    else               l2 = (l % 101) * 64 + (l / 101);  // (c,s)->(s,c)
    xnext[(size_t)l2 * 64 + j] = out;
}

// ---------------- epilogue ----------------
__global__ void k_epilogue(const float* __restrict__ x, const float* __restrict__ Wfc,
                           const float* __restrict__ bfc, const float* __restrict__ ytrue,
                           const int* __restrict__ halfwin, const int* __restrict__ rows,
                           float* __restrict__ out) {
    int k = threadIdx.x;  // 64
    int hw = halfwin[0];
    int c = rows[k];
    const float* xr = x + ((size_t)hw * 64 + c) * 64;
    float acc = bfc[0];
    for (int i = 0; i < 64; i++) acc += xr[i] * Wfc[i];
    float s = 1.f / (1.f + expf(-acc));
    float r = 1.f - fabsf(ytrue[k] - s);
    out[k] = r;
}

extern "C" void kernel_launch(void* const* d_in, const int* in_sizes, int n_in,
                              void* d_out, int out_size, void* d_ws, size_t ws_size,
                              hipStream_t stream) {
    const float* DNA   = (const float*)d_in[0];
    const float* CpG   = (const float*)d_in[1];
    const float* cel   = (const float*)d_in[2];
    const float* pos   = (const float*)d_in[3];
    const float* ytrue = (const float*)d_in[4];
    const float* Wfcc  = (const float*)d_in[5];
    const float* bfcc  = (const float*)d_in[6];
    const float* Win   = (const float*)d_in[7];
    const float* convw = (const float*)d_in[8];
    const float* convb = (const float*)d_in[9];
    const float* Wxp   = (const float*)d_in[10];
    const float* Wdt   = (const float*)d_in[11];
    const float* bdt   = (const float*)d_in[12];
    const float* Alog  = (const float*)d_in[13];
    const float* Dres  = (const float*)d_in[14];
    const float* Wout  = (const float*)d_in[15];
    const float* lng   = (const float*)d_in[16];
    const float* lnb   = (const float*)d_in[17];
    const float* Wfc   = (const float*)d_in[18];
    const float* bfc   = (const float*)d_in[19];
    const int* halfwin = (const int*)d_in[20];
    const int* rows    = (const int*)d_in[21];

    float* ws = (float*)d_ws;
    size_t off = 0;
    float* x0  = ws + off; off += (size_t)L_SEQ * 64;
    float* x1  = ws + off; off += (size_t)L_SEQ * 64;
    float* xz  = ws + off; off += (size_t)L_SEQ * 256;
    float* dtT = ws + off; off += (size_t)2 * 128 * L_SEQ;
    float* xcT = ws + off; off += (size_t)2 * 128 * L_SEQ;
    float* BT  = ws + off; off += (size_t)2 * 16 * L_SEQ;
    float* CT  = ws + off; off += (size_t)2 * 16 * L_SEQ;
    float* y   = ws + off; off += (size_t)2 * L_SEQ * 128;
    float* cA  = ws + off; off += (size_t)2 * NCH * 2048;
    float* cB  = ws + off; off += (size_t)2 * NCH * 2048;
    float* Hi  = ws + off; off += (size_t)2 * NCH * 2048;

    k_embed<<<L_SEQ, 64, 0, stream>>>(DNA, CpG, cel, pos, Wfcc, bfcc, x0);

    float* xcur = x0;
    float* xnxt = x1;
    for (int sb = 0; sb < 8; sb++) {
        k_gemm_in<<<L_SEQ / 8, 256, 0, stream>>>(xcur, Win, xz);
        k_convdt<<<L_SEQ / 16, 256, 0, stream>>>(xz, convw, convb, Wxp, Wdt, bdt,
                                                 dtT, xcT, BT, CT);
        k_scan1s<<<dim3(8, NCH, 2), 256, 0, stream>>>(dtT, xcT, BT, Alog, cA, cB);
        k_scan2p<<<16, 256, 0, stream>>>(cA, cB, Hi);
        k_scan3s<<<dim3(8, NCH, 2), 256, 0, stream>>>(dtT, xcT, BT, CT, Alog, Dres,
                                                      Hi, y);
        k_outln<<<L_SEQ / 4, 256, 0, stream>>>(xcur, y, xz, Wout, lng, lnb, xnxt,
                                               (sb % 2 == 0) ? 0 : 1);
        float* tmp = xcur; xcur = xnxt; xnxt = tmp;
    }

    k_epilogue<<<1, 64, 0, stream>>>(xcur, Wfc, bfc, ytrue, halfwin, rows, (float*)d_out);
}

// Round 10
// 971.204 us; speedup vs baseline: 1.3000x; 1.0157x over previous
//
#include <hip/hip_runtime.h>
#include <hip/hip_bf16.h>
#include <math.h>

#define L_SEQ 6464
#define DM 64
#define DI 128
#define DS 16
#define CHUNK 64
#define NCH 101   // 6464 = 101 * 64; chunk slabs are 16B-aligned
#define YSTR 68   // s_y stride: 17*16B aligned, 2-way bank alias only

typedef unsigned int u32;
// direct-to-LDS DMA, 16B per lane; dest = wave-uniform lds base + lane*16
__device__ __forceinline__ void lds_dma16(const float* g, float* s) {
    __builtin_amdgcn_global_load_lds(
        (const __attribute__((address_space(1))) u32*)g,
        (__attribute__((address_space(3))) u32*)s, 16, 0, 0);
}

// ---------------- prologue: concat + pos, then @W_fcc + b_fcc ----------------
__global__ void k_embed(const float* __restrict__ DNA, const float* __restrict__ CpG,
                        const float* __restrict__ cell, const float* __restrict__ pos,
                        const float* __restrict__ Wfcc, const float* __restrict__ bfcc,
                        float* __restrict__ x0) {
    int l = blockIdx.x;
    int j = threadIdx.x;  // 64
    __shared__ float in64[64];
    float v;
    if (j < 16)       v = CpG[l * 16 + j];
    else if (j < 32)  v = cell[l * 16 + (j - 16)];
    else              v = DNA[l * 32 + (j - 32)];
    v += pos[l * 64 + j];
    in64[j] = v;
    __syncthreads();
    float acc = bfcc[j];
    for (int i = 0; i < 64; i++) acc += in64[i] * Wfcc[i * 64 + j];
    x0[(size_t)l * 64 + j] = acc;
}

// ---------------- xz = x @ W_in : 8 rows/block, f4 LDS reads ----------------
__global__ void __launch_bounds__(256) k_gemm_in(const float* __restrict__ x,
                                                 const float* __restrict__ Win,
                                                 float* __restrict__ xz) {
    __shared__ __align__(16) float s_x[8][64];
    int t0 = blockIdx.x * 8;
    int tid = threadIdx.x;
    for (int i = tid; i < 8 * 64; i += 256) {
        int rr = i >> 6, c = i & 63;
        s_x[rr][c] = x[(size_t)(t0 + rr) * 64 + c];
    }
    __syncthreads();
    int j = tid;  // 256 cols
    float acc[8];
    #pragma unroll
    for (int r = 0; r < 8; r++) acc[r] = 0.f;
    for (int i = 0; i < 64; i += 4) {
        float w0 = Win[(i + 0) * 256 + j];
        float w1 = Win[(i + 1) * 256 + j];
        float w2 = Win[(i + 2) * 256 + j];
        float w3 = Win[(i + 3) * 256 + j];
        #pragma unroll
        for (int r = 0; r < 8; r++) {
            float4 xv = *(const float4*)&s_x[r][i];
            acc[r] = fmaf(xv.x, w0, fmaf(xv.y, w1, fmaf(xv.z, w2, fmaf(xv.w, w3, acc[r]))));
        }
    }
    #pragma unroll
    for (int r = 0; r < 8; r++) xz[(size_t)(t0 + r) * 256 + j] = acc[r];
}

// ------- fused conv(+silu) + xdbl + dt/B/C, one dir per block -> TRANSPOSED outputs -------
__global__ void __launch_bounds__(256) k_convdt(
        const float* __restrict__ xz, const float* __restrict__ convw,
        const float* __restrict__ convb, const float* __restrict__ Wxp,
        const float* __restrict__ Wdt, const float* __restrict__ bdt,
        float* __restrict__ dtT, float* __restrict__ xcT,
        float* __restrict__ BT, float* __restrict__ CT) {
    __shared__ __align__(16) float s_xi[22][128];    // xi rows t0-3 .. t0+18
    __shared__ __align__(16) float s_xc[16][128];
    __shared__ __align__(16) float s_dtl[16][128];
    __shared__ __align__(16) float s_xd[16][36];
    __shared__ __align__(16) float s_wxpT[36 * 132]; // wxpT[t][i], stride 132
    int t0 = blockIdx.x * 16;
    int dir = blockIdx.y;
    int tid = threadIdx.x;
    for (int i = tid; i < 128 * 36; i += 256) {
        int ii = i / 36, t = i - ii * 36;
        s_wxpT[t * 132 + ii] = Wxp[i];
    }
    for (int i = tid; i < 22 * 32; i += 256) {
        int rr = i >> 5, q = i & 31;
        int r = t0 - 3 + rr;
        float4 v = make_float4(0.f, 0.f, 0.f, 0.f);
        if (r >= 0 && r < L_SEQ) v = *(const float4*)&xz[(size_t)r * 256 + 4 * q];
        s_xi[rr][4 * q + 0] = v.x;
        s_xi[rr][4 * q + 1] = v.y;
        s_xi[rr][4 * q + 2] = v.z;
        s_xi[rr][4 * q + 3] = v.w;
    }
    __syncthreads();
    // conv + silu
    for (int i = tid; i < 16 * 128; i += 256) {
        int rr = i >> 7, d = i & 127;
        int lr = rr + 3;
        float acc = convb[d];
        if (dir == 0) {
            #pragma unroll
            for (int k = 0; k < 4; k++) acc += convw[d * 4 + k] * s_xi[lr - 3 + k][d];
        } else {
            #pragma unroll
            for (int k = 0; k < 4; k++) acc += convw[d * 4 + k] * s_xi[lr + 3 - k][d];
        }
        s_xc[rr][d] = acc / (1.f + expf(-acc));
    }
    __syncthreads();
    // xdbl = xc @ W_xp (36 cols)
    for (int o = tid; o < 16 * 36; o += 256) {
        int rr = o / 36, t = o - rr * 36;
        float acc = 0.f;
        for (int i = 0; i < 128; i += 4) {
            float4 xv = *(const float4*)&s_xc[rr][i];
            float4 wv = *(const float4*)&s_wxpT[t * 132 + i];
            acc += xv.x * wv.x + xv.y * wv.y + xv.z * wv.z + xv.w * wv.w;
        }
        s_xd[rr][t] = acc;
    }
    __syncthreads();
    // dt = softplus(xdbl[:, :4] @ W_dt + b_dt)
    for (int o = tid; o < 16 * 128; o += 256) {
        int rr = o >> 7, d = o & 127;
        float pre = bdt[d];
        #pragma unroll
        for (int r = 0; r < 4; r++) pre += s_xd[rr][r] * Wdt[r * 128 + d];
        s_dtl[rr][d] = (pre > 20.f) ? pre : log1pf(expf(pre));
    }
    __syncthreads();
    // transposed stores: dtT/xcT [dir][d][L]
    for (int i = tid; i < 512; i += 256) {
        int q = i >> 7, d = i & 127;
        float4 a, b;
        a.x = s_dtl[4 * q + 0][d]; a.y = s_dtl[4 * q + 1][d];
        a.z = s_dtl[4 * q + 2][d]; a.w = s_dtl[4 * q + 3][d];
        b.x = s_xc[4 * q + 0][d];  b.y = s_xc[4 * q + 1][d];
        b.z = s_xc[4 * q + 2][d];  b.w = s_xc[4 * q + 3][d];
        size_t base = (size_t)(dir * 128 + d) * L_SEQ + t0 + 4 * q;
        *(float4*)&dtT[base] = a;
        *(float4*)&xcT[base] = b;
    }
    // BT/CT [dir][s][L]
    if (tid < 128) {
        int cc = tid >> 2, q = tid & 3;
        float4 v;
        v.x = s_xd[4 * q + 0][4 + cc]; v.y = s_xd[4 * q + 1][4 + cc];
        v.z = s_xd[4 * q + 2][4 + cc]; v.w = s_xd[4 * q + 3][4 + cc];
        float* dst = (cc < 16) ? BT : CT;
        *(float4*)&dst[(size_t)(dir * 16 + (cc & 15)) * L_SEQ + t0 + 4 * q] = v;
    }
}

// ---------------- DPP 16-lane row rotate ----------------
template<int CTRL>
__device__ __forceinline__ float ror16f(float v) {
    return __int_as_float(__builtin_amdgcn_update_dpp(0, __float_as_int(v), CTRL, 0xf, 0xf, true));
}

// ---------------- scan pass 1: LDS-DMA staged per-chunk (a_prod, h_end) ----------------
__global__ void __launch_bounds__(256) k_scan1s(
        const float* __restrict__ dtT, const float* __restrict__ xcT,
        const float* __restrict__ BT, const float* __restrict__ Alog,
        float* __restrict__ cA, float* __restrict__ cB) {
    __shared__ __align__(16) float s_dt[16 * 64];
    __shared__ __align__(16) float s_xc[16 * 64];
    __shared__ __align__(16) float s_B [16 * 64];
    int bxd = blockIdx.x;   // d-group (8)
    int c   = blockIdx.y;   // chunk (101)
    int dir = blockIdx.z;   // 2
    int tid = threadIdx.x;
    int lane = tid & 63, wave = tid >> 6;
    int d0 = bxd * 16;
    int slab = dir ? (L_SEQ - 64 * (c + 1)) : (64 * c);   // physical ascending slab
    // stage: wave w covers 16B-units f = w*64+lane of each 4KB array
    {
        int f = wave * 64 + lane;
        int row = f >> 4, u = f & 15;
        lds_dma16(dtT + (size_t)(dir * 128 + d0 + row) * L_SEQ + slab + 4 * u, s_dt + wave * 256);
        lds_dma16(xcT + (size_t)(dir * 128 + d0 + row) * L_SEQ + slab + 4 * u, s_xc + wave * 256);
        lds_dma16(BT  + (size_t)(dir * 16 + row) * L_SEQ + slab + 4 * u,       s_B  + wave * 256);
    }
    int s = tid & 15, dl = tid >> 4;
    float A = -expf(Alog[(d0 + dl) * 16 + s]);
    __syncthreads();   // drains the DMA (vmcnt) + barrier
    const float4* dq4 = (const float4*)(s_dt + dl * 64);
    const float4* xq4 = (const float4*)(s_xc + dl * 64);
    const float4* bq4 = (const float4*)(s_B + s * 64);
    float h = 0.f, ap = 1.f;
    if (dir == 0) {
        #pragma unroll
        for (int q = 0; q < 16; q++) {
            float4 dv = dq4[q], xv = xq4[q], bv = bq4[q];
            float a;
            a = __expf(dv.x * A); h = fmaf(a, h, dv.x * xv.x * bv.x); ap *= a;
            a = __expf(dv.y * A); h = fmaf(a, h, dv.y * xv.y * bv.y); ap *= a;
            a = __expf(dv.z * A); h = fmaf(a, h, dv.z * xv.z * bv.z); ap *= a;
            a = __expf(dv.w * A); h = fmaf(a, h, dv.w * xv.w * bv.w); ap *= a;
        }
    } else {
        #pragma unroll
        for (int q = 15; q >= 0; q--) {   // physical descending = logical ascending
            float4 dv = dq4[q], xv = xq4[q], bv = bq4[q];
            float a;
            a = __expf(dv.w * A); h = fmaf(a, h, dv.w * xv.w * bv.w); ap *= a;
            a = __expf(dv.z * A); h = fmaf(a, h, dv.z * xv.z * bv.z); ap *= a;
            a = __expf(dv.y * A); h = fmaf(a, h, dv.y * xv.y * bv.y); ap *= a;
            a = __expf(dv.x * A); h = fmaf(a, h, dv.x * xv.x * bv.x); ap *= a;
        }
    }
    size_t o = ((size_t)(dir * NCH + c) << 11) + (size_t)bxd * 256 + tid;
    cA[o] = ap;
    cB[o] = h;
}

// ---------------- scan pass 1.5: serial prefix, compile-time unrolled batches ----------------
__global__ void __launch_bounds__(256) k_scan2p(
        const float* __restrict__ cA, const float* __restrict__ cB,
        float* __restrict__ Hinit) {
    int idx = blockIdx.x * 256 + threadIdx.x;  // 4096
    int dir = idx >> 11;
    int ds = idx & 2047;
    size_t base = ((size_t)(dir * NCH) << 11) + ds;
    float h = 0.f;
    #pragma unroll 1
    for (int b = 0; b < 12; b++) {   // 12 * 8 = 96
        float av[8], bv[8];
        #pragma unroll
        for (int j = 0; j < 8; j++) {
            size_t o = base + ((size_t)(b * 8 + j) << 11);
            av[j] = cA[o];
            bv[j] = cB[o];
        }
        #pragma unroll
        for (int j = 0; j < 8; j++) {
            size_t o = base + ((size_t)(b * 8 + j) << 11);
            Hinit[o] = h;
            h = fmaf(av[j], h, bv[j]);
        }
    }
    {   // tail: 96..100
        float av[5], bv[5];
        #pragma unroll
        for (int j = 0; j < 5; j++) {
            size_t o = base + ((size_t)(96 + j) << 11);
            av[j] = cA[o];
            bv[j] = cB[o];
        }
        #pragma unroll
        for (int j = 0; j < 5; j++) {
            size_t o = base + ((size_t)(96 + j) << 11);
            Hinit[o] = h;
            h = fmaf(av[j], h, bv[j]);
        }
    }
}

// ------- scan pass 2: LDS-DMA staged carry-in replay; y via small LDS transpose -------
#define S3(DV, XV, BV, CV, T)                                        \
    {                                                                \
        float a = __expf((DV) * A);                                  \
        h = fmaf(a, h, (DV) * (XV) * (BV));                          \
        float val = h * (CV);                                        \
        val += ror16f<0x121>(val); val += ror16f<0x122>(val);        \
        val += ror16f<0x124>(val); val += ror16f<0x128>(val);        \
        if (s == 0) s_y[dl * YSTR + (T)] = val + (XV) * Dv;          \
    }

__global__ void __launch_bounds__(256) k_scan3s(
        const float* __restrict__ dtT, const float* __restrict__ xcT,
        const float* __restrict__ BT, const float* __restrict__ CT,
        const float* __restrict__ Alog, const float* __restrict__ Dres,
        const float* __restrict__ Hinit, float* __restrict__ y) {
    __shared__ __align__(16) float s_dt[16 * 64];
    __shared__ __align__(16) float s_xc[16 * 64];
    __shared__ __align__(16) float s_B [16 * 64];
    __shared__ __align__(16) float s_C [16 * 64];
    __shared__ __align__(16) float s_y [16 * YSTR];
    int bxd = blockIdx.x;
    int c   = blockIdx.y;
    int dir = blockIdx.z;
    int tid = threadIdx.x;
    int lane = tid & 63, wave = tid >> 6;
    int d0 = bxd * 16;
    int slab = dir ? (L_SEQ - 64 * (c + 1)) : (64 * c);
    {
        int f = wave * 64 + lane;
        int row = f >> 4, u = f & 15;
        lds_dma16(dtT + (size_t)(dir * 128 + d0 + row) * L_SEQ + slab + 4 * u, s_dt + wave * 256);
        lds_dma16(xcT + (size_t)(dir * 128 + d0 + row) * L_SEQ + slab + 4 * u, s_xc + wave * 256);
        lds_dma16(BT  + (size_t)(dir * 16 + row) * L_SEQ + slab + 4 * u,       s_B  + wave * 256);
        lds_dma16(CT  + (size_t)(dir * 16 + row) * L_SEQ + slab + 4 * u,       s_C  + wave * 256);
    }
    int s = tid & 15, dl = tid >> 4;
    float carry = Hinit[((size_t)(dir * NCH + c) << 11) + (size_t)bxd * 256 + tid];
    float A = -expf(Alog[(d0 + dl) * 16 + s]);
    float Dv = Dres[d0 + dl];
    __syncthreads();   // drains DMA + barrier
    const float4* dq4 = (const float4*)(s_dt + dl * 64);
    const float4* xq4 = (const float4*)(s_xc + dl * 64);
    const float4* bq4 = (const float4*)(s_B + s * 64);
    const float4* cq4 = (const float4*)(s_C + s * 64);
    float h = carry;
    if (dir == 0) {
        #pragma unroll
        for (int q = 0; q < 16; q++) {
            float4 dv = dq4[q], xv = xq4[q], bv = bq4[q], cv = cq4[q];
            S3(dv.x, xv.x, bv.x, cv.x, 4 * q + 0)
            S3(dv.y, xv.y, bv.y, cv.y, 4 * q + 1)
            S3(dv.z, xv.z, bv.z, cv.z, 4 * q + 2)
            S3(dv.w, xv.w, bv.w, cv.w, 4 * q + 3)
        }
    } else {
        #pragma unroll
        for (int q = 15; q >= 0; q--) {   // logical t = 63 - physical p
            float4 dv = dq4[q], xv = xq4[q], bv = bq4[q], cv = cq4[q];
            S3(dv.w, xv.w, bv.w, cv.w, 63 - (4 * q + 3))
            S3(dv.z, xv.z, bv.z, cv.z, 63 - (4 * q + 2))
            S3(dv.y, xv.y, bv.y, cv.y, 63 - (4 * q + 1))
            S3(dv.x, xv.x, bv.x, cv.x, 63 - (4 * q + 0))
        }
    }
    __syncthreads();
    // write y row-major: lane mapping t-major for coalesced 64B segments
    {
        int dd = tid & 15, q = tid >> 4;
        int dg = bxd * 16 + dd;
        float4 v = *(const float4*)&s_y[dd * YSTR + 4 * q];
        float* yp = y + (size_t)dir * L_SEQ * 128;
        if (dir == 0) {
            int r0 = c * 64 + 4 * q;
            yp[(size_t)(r0 + 0) * 128 + dg] = v.x;
            yp[(size_t)(r0 + 1) * 128 + dg] = v.y;
            yp[(size_t)(r0 + 2) * 128 + dg] = v.z;
            yp[(size_t)(r0 + 3) * 128 + dg] = v.w;
        } else {
            int r0 = L_SEQ - 1 - (c * 64 + 4 * q);
            yp[(size_t)(r0 - 0) * 128 + dg] = v.x;
            yp[(size_t)(r0 - 1) * 128 + dg] = v.y;
            yp[(size_t)(r0 - 2) * 128 + dg] = v.z;
            yp[(size_t)(r0 - 3) * 128 + dg] = v.w;
        }
    }
}

// ------- out-GEMM + silu(z) gate + residual + layernorm + permute; 4 rows/block -------
__global__ void __launch_bounds__(256) k_outln(
        const float* __restrict__ x, const float* __restrict__ y,
        const float* __restrict__ xz, const float* __restrict__ Wout,
        const float* __restrict__ lng, const float* __restrict__ lnb,
        float* __restrict__ xnext, int permMode) {
    __shared__ __align__(16) float s_g[4][128];
    int w = threadIdx.x >> 6;
    int j = threadIdx.x & 63;
    int l = blockIdx.x * 4 + w;
    float z1 = xz[(size_t)l * 256 + 128 + j];
    float z2 = xz[(size_t)l * 256 + 192 + j];
    float sz1 = z1 / (1.f + expf(-z1));
    float sz2 = z2 / (1.f + expf(-z2));
    s_g[w][j]      = 0.5f * (y[(size_t)l * 128 + j] + y[(size_t)(L_SEQ + l) * 128 + j]) * sz1;
    s_g[w][j + 64] = 0.5f * (y[(size_t)l * 128 + 64 + j] + y[(size_t)(L_SEQ + l) * 128 + 64 + j]) * sz2;
    __syncthreads();
    float acc = x[(size_t)l * 64 + j];
    for (int i = 0; i < 128; i += 4) {
        float4 gv = *(const float4*)&s_g[w][i];
        acc = fmaf(gv.x, Wout[(i + 0) * 64 + j], acc);
        acc = fmaf(gv.y, Wout[(i + 1) * 64 + j], acc);
        acc = fmaf(gv.z, Wout[(i + 2) * 64 + j], acc);
        acc = fmaf(gv.w, Wout[(i + 3) * 64 + j], acc);
    }
    float m = acc;
    for (int o = 32; o >= 1; o >>= 1) m += __shfl_xor(m, o);
    m *= (1.f / 64.f);
    float dv = acc - m;
    float v = dv * dv;
    for (int o = 32; o >= 1; o >>= 1) v += __shfl_xor(v, o);
    v *= (1.f / 64.f);
    float out = dv * rsqrtf(v + 1e-5f) * lng[j] + lnb[j];
    int l2;
    if (permMode == 0) l2 = (l % 64) * 101 + (l / 64);   // (s,c)->(c,s)
    else               l2 = (l % 101) * 64 + (l / 101);  // (c,s)->(s,c)
    xnext[(size_t)l2 * 64 + j] = out;
}

// ---------------- epilogue ----------------
__global__ void k_epilogue(const float* __restrict__ x, const float* __restrict__ Wfc,
                           const float* __restrict__ bfc, const float* __restrict__ ytrue,
                           const int* __restrict__ halfwin, const int* __restrict__ rows,
                           float* __restrict__ out) {
    int k = threadIdx.x;  // 64
    int hw = halfwin[0];
    int c = rows[k];
    const float* xr = x + ((size_t)hw * 64 + c) * 64;
    float acc = bfc[0];
    for (int i = 0; i < 64; i++) acc += xr[i] * Wfc[i];
    float s = 1.f / (1.f + expf(-acc));
    float r = 1.f - fabsf(ytrue[k] - s);
    out[k] = r;
}

extern "C" void kernel_launch(void* const* d_in, const int* in_sizes, int n_in,
                              void* d_out, int out_size, void* d_ws, size_t ws_size,
                              hipStream_t stream) {
    const float* DNA   = (const float*)d_in[0];
    const float* CpG   = (const float*)d_in[1];
    const float* cel   = (const float*)d_in[2];
    const float* pos   = (const float*)d_in[3];
    const float* ytrue = (const float*)d_in[4];
    const float* Wfcc  = (const float*)d_in[5];
    const float* bfcc  = (const float*)d_in[6];
    const float* Win   = (const float*)d_in[7];
    const float* convw = (const float*)d_in[8];
    const float* convb = (const float*)d_in[9];
    const float* Wxp   = (const float*)d_in[10];
    const float* Wdt   = (const float*)d_in[11];
    const float* bdt   = (const float*)d_in[12];
    const float* Alog  = (const float*)d_in[13];
    const float* Dres  = (const float*)d_in[14];
    const float* Wout  = (const float*)d_in[15];
    const float* lng   = (const float*)d_in[16];
    const float* lnb   = (const float*)d_in[17];
    const float* Wfc   = (const float*)d_in[18];
    const float* bfc   = (const float*)d_in[19];
    const int* halfwin = (const int*)d_in[20];
    const int* rows    = (const int*)d_in[21];

    float* ws = (float*)d_ws;
    size_t off = 0;
    float* x0  = ws + off; off += (size_t)L_SEQ * 64;
    float* x1  = ws + off; off += (size_t)L_SEQ * 64;
    float* xz  = ws + off; off += (size_t)L_SEQ * 256;
    float* dtT = ws + off; off += (size_t)2 * 128 * L_SEQ;
    float* xcT = ws + off; off += (size_t)2 * 128 * L_SEQ;
    float* BT  = ws + off; off += (size_t)2 * 16 * L_SEQ;
    float* CT  = ws + off; off += (size_t)2 * 16 * L_SEQ;
    float* y   = ws + off; off += (size_t)2 * L_SEQ * 128;
    float* cA  = ws + off; off += (size_t)2 * NCH * 2048;
    float* cB  = ws + off; off += (size_t)2 * NCH * 2048;
    float* Hi  = ws + off; off += (size_t)2 * NCH * 2048;

    k_embed<<<L_SEQ, 64, 0, stream>>>(DNA, CpG, cel, pos, Wfcc, bfcc, x0);

    float* xcur = x0;
    float* xnxt = x1;
    for (int sb = 0; sb < 8; sb++) {
        k_gemm_in<<<L_SEQ / 8, 256, 0, stream>>>(xcur, Win, xz);
        k_convdt<<<dim3(L_SEQ / 16, 2), 256, 0, stream>>>(xz, convw, convb, Wxp, Wdt, bdt,
                                                          dtT, xcT, BT, CT);
        k_scan1s<<<dim3(8, NCH, 2), 256, 0, stream>>>(dtT, xcT, BT, Alog, cA, cB);
        k_scan2p<<<16, 256, 0, stream>>>(cA, cB, Hi);
        k_scan3s<<<dim3(8, NCH, 2), 256, 0, stream>>>(dtT, xcT, BT, CT, Alog, Dres,
                                                      Hi, y);
        k_outln<<<L_SEQ / 4, 256, 0, stream>>>(xcur, y, xz, Wout, lng, lnb, xnxt,
                                               (sb % 2 == 0) ? 0 : 1);
        float* tmp = xcur; xcur = xnxt; xnxt = tmp;
    }

    k_epilogue<<<1, 64, 0, stream>>>(xcur, Wfc, bfc, ytrue, halfwin, rows, (float*)d_out);
}